// Round 4
// baseline (264.689 us; speedup 1.0000x reference)
//
#include <hip/hip_runtime.h>

#define D_MODEL 1024
#define N_HEADS 16
#define D_KH    64
#define BATCH   4
#define SEQ     2048
#define M_TOTAL (BATCH*SEQ)   // 8192

typedef __attribute__((ext_vector_type(8))) short short8;
typedef __attribute__((ext_vector_type(4))) float f32x4;
typedef __attribute__((ext_vector_type(4))) unsigned short u16x4;
typedef __attribute__((ext_vector_type(2))) unsigned int u32x2;

__device__ __forceinline__ unsigned short f2bf(float f) {
  union { float f; unsigned u; } v; v.f = f;
  unsigned r = v.u + 0x7FFFu + ((v.u >> 16) & 1u);
  return (unsigned short)(r >> 16);
}
__device__ __forceinline__ unsigned fbits(float f) {
  union { float f; unsigned u; } v; v.f = f; return v.u;
}

// ---------------------------------------------------------------- cvt_q
__global__ __launch_bounds__(256) void cvt_q(const float* __restrict__ Q,
                                             unsigned short* __restrict__ Qbf) {
  size_t i = (size_t)blockIdx.x * 256 + threadIdx.x;
  float4 v = ((const float4*)Q)[i];
  u16x4 o;
  o[0] = f2bf(v.x); o[1] = f2bf(v.y); o[2] = f2bf(v.z); o[3] = f2bf(v.w);
  ((u16x4*)Qbf)[i] = o;
}

// ---------------------------------------------------------------- cvt_wt
__global__ __launch_bounds__(256) void cvt_wt(const float* __restrict__ Wq,
                                              const float* __restrict__ Wk,
                                              const float* __restrict__ Wv,
                                              unsigned short* __restrict__ WT) {
  const int z = blockIdx.z;
  const float* W = (z == 0) ? Wq : (z == 1) ? Wk : Wv;
  __shared__ float tile[32][33];
  const int k0 = blockIdx.y * 32, n0 = blockIdx.x * 32;
  const int tx = threadIdx.x & 31, ty = threadIdx.x >> 5;
  for (int i = 0; i < 4; ++i)
    tile[ty + i * 8][tx] = W[(size_t)(k0 + ty + i * 8) * D_MODEL + n0 + tx];
  __syncthreads();
  unsigned short* out = WT + (size_t)z * D_MODEL * D_MODEL;
  for (int i = 0; i < 4; ++i)
    out[(size_t)(n0 + ty + i * 8) * D_MODEL + k0 + tx] = f2bf(tile[tx][ty + i * 8]);
}

// ---------------------------------------------------------------- gemm_qkv
#define BM 128
#define BN 128
#define BK 32

__global__ __launch_bounds__(256, 2) void gemm_qkv(
    const unsigned short* __restrict__ Qbf,
    const unsigned short* __restrict__ WT,
    const float* __restrict__ bq_p, const float* __restrict__ bk_p,
    const float* __restrict__ bv_p,
    float* __restrict__ out_qa,
    unsigned short* __restrict__ kbf,
    unsigned short* __restrict__ vt) {
  const int z  = blockIdx.z;
  const int n0 = blockIdx.x * BN;
  const int m0 = blockIdx.y * BM;
  const int K  = D_MODEL;

  __shared__ unsigned short smA[BM * BK];
  __shared__ unsigned short smB[BN * BK];

  const int t    = threadIdx.x;
  const int lane = t & 63;
  const int w    = t >> 6;
  const int quad = lane >> 4;
  const int l16  = lane & 15;
  const int wr   = w >> 1, wc = w & 1;

  const unsigned short* Wz = WT + (size_t)z * D_MODEL * D_MODEL;

  f32x4 acc[4][4];
  for (int i = 0; i < 4; ++i)
    for (int j = 0; j < 4; ++j) acc[i][j] = (f32x4){0.f, 0.f, 0.f, 0.f};

  for (int k0 = 0; k0 < K; k0 += BK) {
    __syncthreads();
    for (int it = 0; it < 2; ++it) {
      int c   = t + it * 256;
      int row = c >> 2, col = (c & 3) * 8;
      const unsigned short* ga = Qbf + (size_t)(m0 + row) * K + k0 + col;
      const unsigned short* gb = Wz  + (size_t)(n0 + row) * K + k0 + col;
      __builtin_amdgcn_global_load_lds(
          (const __attribute__((address_space(1))) void*)ga,
          (__attribute__((address_space(3))) void*)&smA[c * 8], 16, 0, 0);
      __builtin_amdgcn_global_load_lds(
          (const __attribute__((address_space(1))) void*)gb,
          (__attribute__((address_space(3))) void*)&smB[c * 8], 16, 0, 0);
    }
    __syncthreads();

    short8 afr[4], bfr[4];
    for (int mi = 0; mi < 4; ++mi)
      afr[mi] = *(const short8*)&smA[(wr * 64 + mi * 16 + l16) * BK + quad * 8];
    for (int ni = 0; ni < 4; ++ni)
      bfr[ni] = *(const short8*)&smB[(wc * 64 + ni * 16 + l16) * BK + quad * 8];
    for (int mi = 0; mi < 4; ++mi)
      for (int ni = 0; ni < 4; ++ni)
        acc[mi][ni] = __builtin_amdgcn_mfma_f32_16x16x32_bf16(
            afr[mi], bfr[ni], acc[mi][ni], 0, 0, 0);
  }

  const float* bias = (z == 0) ? bq_p : (z == 1) ? bk_p : bv_p;
  if (z == 2) {
    for (int ni = 0; ni < 4; ++ni) {
      int n = n0 + wc * 64 + ni * 16 + l16;
      float bval = bias[n];
      int h = n >> 6, d = n & 63;
      for (int mi = 0; mi < 4; ++mi) {
        int m = m0 + wr * 64 + mi * 16 + quad * 4;
        int b = m >> 11, s = m & 2047;
        u16x4 o;
        for (int j = 0; j < 4; ++j) o[j] = f2bf(acc[mi][ni][j] + bval);
        *(u16x4*)&vt[(size_t)((b * 16 + h) * 64 + d) * SEQ + s] = o;
      }
    }
  } else {
    for (int ni = 0; ni < 4; ++ni) {
      int n = n0 + wc * 64 + ni * 16 + l16;
      float bval = bias[n];
      for (int mi = 0; mi < 4; ++mi) {
        int mbase = m0 + wr * 64 + mi * 16 + quad * 4;
        for (int j = 0; j < 4; ++j) {
          float v = acc[mi][ni][j] + bval;
          size_t idx = (size_t)(mbase + j) * D_MODEL + n;
          if (z == 0) out_qa[idx] = v;
          else        kbf[idx] = f2bf(v);
        }
      }
    }
  }
}

// ---------------------------------------------------------------- attn
// Block: 128 queries x one (b,h); 4 waves, wave w owns 32 q (2 groups of 16).
#define PST 72   // LDS row stride (elements)
#define QT  128

__global__ __launch_bounds__(256, 2) void attn(
    const float* __restrict__ qa,            // [8192,1024] fp32
    const unsigned short* __restrict__ kbf,  // [8192,1024] bf16
    const unsigned short* __restrict__ vt,   // [(bh)*64+d][2048] bf16 (V^T)
    const int* __restrict__ length,
    float* __restrict__ ctx) {               // [8192,1024] fp32
  const int qt = blockIdx.x;            // 0..15
  const int bh = blockIdx.y;            // 0..63
  const int b = bh >> 4, h = bh & 15;
  const int len = length[b];

  const int t    = threadIdx.x;
  const int lane = t & 63;
  const int w    = t >> 6;
  const int quad = lane >> 4;
  const int l16  = lane & 15;
  const int r8   = t >> 3;              // 0..31
  const int c8   = (t & 7) * 8;         // 0,8,..,56

  __shared__ unsigned short sQ[QT * PST];   // [q][d], Q pre-scaled by SCL
  __shared__ unsigned short sK[64 * PST];   // [k][d]
  __shared__ unsigned short sVT[64 * PST];  // [d][k]
  __shared__ unsigned short sP[QT * PST];   // [q][k]

  const float SCL = 0.125f * 1.44269504f;   // 1/sqrt(64) * log2(e), folded into Q

  // stage Q tile (fp32 -> bf16, pre-scaled)
  for (int half = 0; half < 4; ++half) {
    int r = r8 + half * 32;
    const float* src = qa + (size_t)(b * SEQ + qt * QT + r) * D_MODEL + h * D_KH + c8;
    float4 v0 = *(const float4*)src;
    float4 v1 = *(const float4*)(src + 4);
    short8 o;
    o[0] = (short)f2bf(v0.x * SCL); o[1] = (short)f2bf(v0.y * SCL);
    o[2] = (short)f2bf(v0.z * SCL); o[3] = (short)f2bf(v0.w * SCL);
    o[4] = (short)f2bf(v1.x * SCL); o[5] = (short)f2bf(v1.y * SCL);
    o[6] = (short)f2bf(v1.z * SCL); o[7] = (short)f2bf(v1.w * SCL);
    *(short8*)&sQ[r * PST + c8] = o;
  }
  __syncthreads();

  // loop-invariant Q fragments: group g covers q rows w*32 + g*16 + l16
  short8 qf[2][2];
  for (int g = 0; g < 2; ++g) {
    qf[g][0] = *(const short8*)&sQ[(w * 32 + g * 16 + l16) * PST + quad * 8];
    qf[g][1] = *(const short8*)&sQ[(w * 32 + g * 16 + l16) * PST + 32 + quad * 8];
  }

  f32x4 accpv[2][4];
  for (int g = 0; g < 2; ++g)
    for (int i = 0; i < 4; ++i) accpv[g][i] = (f32x4){0.f, 0.f, 0.f, 0.f};
  float den[2] = {0.f, 0.f};

  const unsigned short* kbase_p = kbf + (size_t)b * SEQ * D_MODEL + h * D_KH;
  const unsigned short* vbase_p = vt + (size_t)bh * 64 * SEQ;

  const int nkt = (len + 63) >> 6;
  for (int kt = 0; kt < nkt; ++kt) {
    __syncthreads();   // prev-iter readers of sK/sVT done
    for (int half = 0; half < 2; ++half) {
      int r = r8 + half * 32;
      *(short8*)&sK[r * PST + c8] =
          *(const short8*)(kbase_p + (size_t)(kt * 64 + r) * D_MODEL + c8);
      *(short8*)&sVT[r * PST + c8] =
          *(const short8*)(vbase_p + (size_t)r * SEQ + kt * 64 + c8);
    }
    __syncthreads();   // staging visible

    const bool full = ((kt + 1) << 6) <= len;   // block-uniform

    // S^T = K.Q^T : per n-block of 16 keys, per group g of 16 queries
    for (int n = 0; n < 4; ++n) {
      short8 kf0 = *(const short8*)&sK[(n * 16 + l16) * PST + quad * 8];
      short8 kf1 = *(const short8*)&sK[(n * 16 + l16) * PST + 32 + quad * 8];
      int kb = kt * 64 + n * 16 + quad * 4;
      for (int g = 0; g < 2; ++g) {
        f32x4 s = (f32x4){0.f, 0.f, 0.f, 0.f};
        s = __builtin_amdgcn_mfma_f32_16x16x32_bf16(kf0, qf[g][0], s, 0, 0, 0);
        s = __builtin_amdgcn_mfma_f32_16x16x32_bf16(kf1, qf[g][1], s, 0, 0, 0);
        float e0, e1, e2, e3;
        if (full) {
          e0 = exp2f(s[0]); e1 = exp2f(s[1]);
          e2 = exp2f(s[2]); e3 = exp2f(s[3]);
        } else {
          e0 = (kb + 0 < len) ? exp2f(s[0]) : 0.f;
          e1 = (kb + 1 < len) ? exp2f(s[1]) : 0.f;
          e2 = (kb + 2 < len) ? exp2f(s[2]) : 0.f;
          e3 = (kb + 3 < len) ? exp2f(s[3]) : 0.f;
        }
        den[g] += (e0 + e1) + (e2 + e3);
        u32x2 pk;
        pk[0] = __builtin_amdgcn_perm(fbits(e1), fbits(e0), 0x07060302);
        pk[1] = __builtin_amdgcn_perm(fbits(e3), fbits(e2), 0x07060302);
        *(u32x2*)&sP[(w * 32 + g * 16 + l16) * PST + n * 16 + quad * 4] = pk;
      }
    }
    // sP rows are per-wave -> no barrier before PV

    // ctx^T += V^T . P^T : D[d=quad*4+j][q=l16], vf shared across groups
    short8 pf[2][2];
    for (int g = 0; g < 2; ++g) {
      pf[g][0] = *(const short8*)&sP[(w * 32 + g * 16 + l16) * PST + quad * 8];
      pf[g][1] = *(const short8*)&sP[(w * 32 + g * 16 + l16) * PST + 32 + quad * 8];
    }
    for (int n2 = 0; n2 < 4; ++n2) {
      short8 vf0 = *(const short8*)&sVT[(n2 * 16 + l16) * PST + quad * 8];
      short8 vf1 = *(const short8*)&sVT[(n2 * 16 + l16) * PST + 32 + quad * 8];
      for (int g = 0; g < 2; ++g) {
        accpv[g][n2] = __builtin_amdgcn_mfma_f32_16x16x32_bf16(vf0, pf[g][0], accpv[g][n2], 0, 0, 0);
        accpv[g][n2] = __builtin_amdgcn_mfma_f32_16x16x32_bf16(vf1, pf[g][1], accpv[g][n2], 0, 0, 0);
      }
    }
  }

  // den per lane for query l16 of group g; reduce over quad replicas
  for (int g = 0; g < 2; ++g) {
    float d = den[g];
    d += __shfl_xor(d, 16, 64);
    d += __shfl_xor(d, 32, 64);
    den[g] = 1.f / (d + 1e-8f);
  }

  // output: thread holds ctx[q = w*32+g*16+l16][d = n2*16 + quad*4 + j]
  for (int g = 0; g < 2; ++g) {
    int q = qt * QT + w * 32 + g * 16 + l16;
    float* dst = ctx + (size_t)(b * SEQ + q) * D_MODEL + h * D_KH;
    float inv = den[g];
    for (int n2 = 0; n2 < 4; ++n2) {
      f32x4 o = accpv[g][n2];
      float4 v = make_float4(o[0] * inv, o[1] * inv, o[2] * inv, o[3] * inv);
      *(float4*)(dst + n2 * 16 + quad * 4) = v;
    }
  }
}

// ---------------------------------------------------------------- launch
extern "C" void kernel_launch(void* const* d_in, const int* in_sizes, int n_in,
                              void* d_out, int out_size, void* d_ws, size_t ws_size,
                              hipStream_t stream) {
  const float* Q      = (const float*)d_in[0];
  const int*   length = (const int*)d_in[1];
  const float* Wq     = (const float*)d_in[2];
  const float* bq     = (const float*)d_in[3];
  const float* Wk     = (const float*)d_in[4];
  const float* bk     = (const float*)d_in[5];
  const float* Wv     = (const float*)d_in[6];
  const float* bv     = (const float*)d_in[7];

  float* out_ctx = (float*)d_out;                         // [8192,1024]
  float* out_qa  = out_ctx + (size_t)M_TOTAL * D_MODEL;   // [8192,1024]

  char* ws = (char*)d_ws;
  unsigned short* Qbf = (unsigned short*)ws;                              // 16 MB
  unsigned short* WT  = (unsigned short*)(ws + (size_t)16 * 1024 * 1024); //  6 MB
  unsigned short* Kbf = (unsigned short*)(ws + (size_t)22 * 1024 * 1024); // 16 MB
  unsigned short* Vt  = (unsigned short*)(ws + (size_t)38 * 1024 * 1024); // 16 MB

  hipLaunchKernelGGL(cvt_q, dim3((M_TOTAL * D_MODEL) / (256 * 4)), dim3(256), 0, stream,
                     Q, Qbf);
  hipLaunchKernelGGL(cvt_wt, dim3(32, 32, 3), dim3(256), 0, stream, Wq, Wk, Wv, WT);
  hipLaunchKernelGGL(gemm_qkv, dim3(D_MODEL / BN, M_TOTAL / BM, 3), dim3(256), 0, stream,
                     Qbf, WT, bq, bk, bv, out_qa, Kbf, Vt);
  hipLaunchKernelGGL(attn, dim3(SEQ / QT, BATCH * N_HEADS), dim3(256), 0, stream,
                     out_qa, Kbf, Vt, length, out_ctx);
}

// Round 5
// 260.742 us; speedup vs baseline: 1.0151x; 1.0151x over previous
//
#include <hip/hip_runtime.h>

#define D_MODEL 1024
#define N_HEADS 16
#define D_KH    64
#define BATCH   4
#define SEQ     2048
#define M_TOTAL (BATCH*SEQ)   // 8192

typedef __attribute__((ext_vector_type(8))) short short8;
typedef __attribute__((ext_vector_type(4))) float f32x4;
typedef __attribute__((ext_vector_type(4))) unsigned short u16x4;
typedef __attribute__((ext_vector_type(2))) unsigned int u32x2;

__device__ __forceinline__ unsigned short f2bf(float f) {
  union { float f; unsigned u; } v; v.f = f;
  unsigned r = v.u + 0x7FFFu + ((v.u >> 16) & 1u);
  return (unsigned short)(r >> 16);
}
__device__ __forceinline__ unsigned fbits(float f) {
  union { float f; unsigned u; } v; v.f = f; return v.u;
}

// ---------------------------------------------------------------- cvt_q
__global__ __launch_bounds__(256) void cvt_q(const float* __restrict__ Q,
                                             unsigned short* __restrict__ Qbf) {
  size_t i = (size_t)blockIdx.x * 256 + threadIdx.x;
  float4 v = ((const float4*)Q)[i];
  u16x4 o;
  o[0] = f2bf(v.x); o[1] = f2bf(v.y); o[2] = f2bf(v.z); o[3] = f2bf(v.w);
  ((u16x4*)Qbf)[i] = o;
}

// ---------------------------------------------------------------- cvt_wt
__global__ __launch_bounds__(256) void cvt_wt(const float* __restrict__ Wq,
                                              const float* __restrict__ Wk,
                                              const float* __restrict__ Wv,
                                              unsigned short* __restrict__ WT) {
  const int z = blockIdx.z;
  const float* W = (z == 0) ? Wq : (z == 1) ? Wk : Wv;
  __shared__ float tile[32][33];
  const int k0 = blockIdx.y * 32, n0 = blockIdx.x * 32;
  const int tx = threadIdx.x & 31, ty = threadIdx.x >> 5;
  for (int i = 0; i < 4; ++i)
    tile[ty + i * 8][tx] = W[(size_t)(k0 + ty + i * 8) * D_MODEL + n0 + tx];
  __syncthreads();
  unsigned short* out = WT + (size_t)z * D_MODEL * D_MODEL;
  for (int i = 0; i < 4; ++i)
    out[(size_t)(n0 + ty + i * 8) * D_MODEL + k0 + tx] = f2bf(tile[tx][ty + i * 8]);
}

// ---------------------------------------------------------------- gemm_qkv
#define BM 128
#define BN 128
#define BK 32

__global__ __launch_bounds__(256, 2) void gemm_qkv(
    const unsigned short* __restrict__ Qbf,
    const unsigned short* __restrict__ WT,
    const float* __restrict__ bq_p, const float* __restrict__ bk_p,
    const float* __restrict__ bv_p,
    float* __restrict__ out_qa,
    unsigned short* __restrict__ kbf,
    unsigned short* __restrict__ vt) {
  const int z  = blockIdx.z;
  const int n0 = blockIdx.x * BN;
  const int m0 = blockIdx.y * BM;
  const int K  = D_MODEL;

  __shared__ unsigned short smA[BM * BK];
  __shared__ unsigned short smB[BN * BK];

  const int t    = threadIdx.x;
  const int lane = t & 63;
  const int w    = t >> 6;
  const int quad = lane >> 4;
  const int l16  = lane & 15;
  const int wr   = w >> 1, wc = w & 1;

  const unsigned short* Wz = WT + (size_t)z * D_MODEL * D_MODEL;

  f32x4 acc[4][4];
  for (int i = 0; i < 4; ++i)
    for (int j = 0; j < 4; ++j) acc[i][j] = (f32x4){0.f, 0.f, 0.f, 0.f};

  for (int k0 = 0; k0 < K; k0 += BK) {
    __syncthreads();
    for (int it = 0; it < 2; ++it) {
      int c   = t + it * 256;
      int row = c >> 2, col = (c & 3) * 8;
      const unsigned short* ga = Qbf + (size_t)(m0 + row) * K + k0 + col;
      const unsigned short* gb = Wz  + (size_t)(n0 + row) * K + k0 + col;
      __builtin_amdgcn_global_load_lds(
          (const __attribute__((address_space(1))) void*)ga,
          (__attribute__((address_space(3))) void*)&smA[c * 8], 16, 0, 0);
      __builtin_amdgcn_global_load_lds(
          (const __attribute__((address_space(1))) void*)gb,
          (__attribute__((address_space(3))) void*)&smB[c * 8], 16, 0, 0);
    }
    __syncthreads();

    short8 afr[4], bfr[4];
    for (int mi = 0; mi < 4; ++mi)
      afr[mi] = *(const short8*)&smA[(wr * 64 + mi * 16 + l16) * BK + quad * 8];
    for (int ni = 0; ni < 4; ++ni)
      bfr[ni] = *(const short8*)&smB[(wc * 64 + ni * 16 + l16) * BK + quad * 8];
    for (int mi = 0; mi < 4; ++mi)
      for (int ni = 0; ni < 4; ++ni)
        acc[mi][ni] = __builtin_amdgcn_mfma_f32_16x16x32_bf16(
            afr[mi], bfr[ni], acc[mi][ni], 0, 0, 0);
  }

  const float* bias = (z == 0) ? bq_p : (z == 1) ? bk_p : bv_p;
  if (z == 2) {
    for (int ni = 0; ni < 4; ++ni) {
      int n = n0 + wc * 64 + ni * 16 + l16;
      float bval = bias[n];
      int h = n >> 6, d = n & 63;
      for (int mi = 0; mi < 4; ++mi) {
        int m = m0 + wr * 64 + mi * 16 + quad * 4;
        int b = m >> 11, s = m & 2047;
        u16x4 o;
        for (int j = 0; j < 4; ++j) o[j] = f2bf(acc[mi][ni][j] + bval);
        *(u16x4*)&vt[(size_t)((b * 16 + h) * 64 + d) * SEQ + s] = o;
      }
    }
  } else {
    for (int ni = 0; ni < 4; ++ni) {
      int n = n0 + wc * 64 + ni * 16 + l16;
      float bval = bias[n];
      for (int mi = 0; mi < 4; ++mi) {
        int mbase = m0 + wr * 64 + mi * 16 + quad * 4;
        for (int j = 0; j < 4; ++j) {
          float v = acc[mi][ni][j] + bval;
          size_t idx = (size_t)(mbase + j) * D_MODEL + n;
          if (z == 0) out_qa[idx] = v;
          else        kbf[idx] = f2bf(v);
        }
      }
    }
  }
}

// ---------------------------------------------------------------- attn
// Block: 64 queries x one (b,h); 4 waves, wave w owns 16 queries.
// Register-prefetch pipeline: next K/V tile loads overlap current compute.
#define PST 72   // LDS row stride (elements)

__global__ __launch_bounds__(256, 4) void attn(
    const float* __restrict__ qa,            // [8192,1024] fp32
    const unsigned short* __restrict__ kbf,  // [8192,1024] bf16
    const unsigned short* __restrict__ vt,   // [(bh)*64+d][2048] bf16 (V^T)
    const int* __restrict__ length,
    float* __restrict__ ctx) {               // [8192,1024] fp32
  const int qt = blockIdx.x;            // 0..31
  const int bh = blockIdx.y;            // 0..63
  const int b = bh >> 4, h = bh & 15;
  const int len = length[b];

  const int t    = threadIdx.x;
  const int lane = t & 63;
  const int w    = t >> 6;
  const int quad = lane >> 4;
  const int l16  = lane & 15;
  const int r8   = t >> 3;              // 0..31
  const int c8   = (t & 7) * 8;         // 0,8,..,56

  __shared__ unsigned short sQ[64 * PST];   // [q][d], pre-scaled
  __shared__ unsigned short sK[64 * PST];   // [k][d]
  __shared__ unsigned short sVT[64 * PST];  // [d][k]
  __shared__ unsigned short sP[64 * PST];   // [q][k]

  const float SCL = 0.125f * 1.44269504f;   // 1/sqrt(64) * log2(e)

  // stage Q tile (fp32 -> bf16, pre-scaled)
  for (int half = 0; half < 2; ++half) {
    int r = r8 + half * 32;
    const float* src = qa + (size_t)(b * SEQ + qt * 64 + r) * D_MODEL + h * D_KH + c8;
    float4 v0 = *(const float4*)src;
    float4 v1 = *(const float4*)(src + 4);
    short8 o;
    o[0] = (short)f2bf(v0.x * SCL); o[1] = (short)f2bf(v0.y * SCL);
    o[2] = (short)f2bf(v0.z * SCL); o[3] = (short)f2bf(v0.w * SCL);
    o[4] = (short)f2bf(v1.x * SCL); o[5] = (short)f2bf(v1.y * SCL);
    o[6] = (short)f2bf(v1.z * SCL); o[7] = (short)f2bf(v1.w * SCL);
    *(short8*)&sQ[r * PST + c8] = o;
  }
  __syncthreads();

  short8 qf0 = *(const short8*)&sQ[(w * 16 + l16) * PST + quad * 8];
  short8 qf1 = *(const short8*)&sQ[(w * 16 + l16) * PST + 32 + quad * 8];

  f32x4 accpv[4];
  for (int i = 0; i < 4; ++i) accpv[i] = (f32x4){0.f, 0.f, 0.f, 0.f};
  float den = 0.f;

  const unsigned short* kbase_p = kbf + (size_t)b * SEQ * D_MODEL + h * D_KH;
  const unsigned short* vbase_p = vt + (size_t)bh * 64 * SEQ;

  const int nkt = (len + 63) >> 6;

  // prefetch tile 0 into registers
  short8 rk[2], rv[2];
  for (int half = 0; half < 2; ++half) {
    int r = r8 + half * 32;
    rk[half] = *(const short8*)(kbase_p + (size_t)r * D_MODEL + c8);
    rv[half] = *(const short8*)(vbase_p + (size_t)r * SEQ + c8);
  }

  for (int kt = 0; kt < nkt; ++kt) {
    __syncthreads();   // prev-iter readers of sK/sVT done
    for (int half = 0; half < 2; ++half) {
      int r = r8 + half * 32;
      *(short8*)&sK[r * PST + c8]  = rk[half];
      *(short8*)&sVT[r * PST + c8] = rv[half];
    }
    __syncthreads();   // staging visible

    // issue next tile's global loads; latency overlaps compute below
    if (kt + 1 < nkt) {
      for (int half = 0; half < 2; ++half) {
        int r = r8 + half * 32;
        rk[half] = *(const short8*)(kbase_p + (size_t)((kt + 1) * 64 + r) * D_MODEL + c8);
        rv[half] = *(const short8*)(vbase_p + (size_t)r * SEQ + (kt + 1) * 64 + c8);
      }
    }

    const bool full = ((kt + 1) << 6) <= len;   // block-uniform

    // S^T = K.Q^T : D[key=quad*4+j][q=l16] per n-block of 16 keys
    for (int n = 0; n < 4; ++n) {
      short8 kf0 = *(const short8*)&sK[(n * 16 + l16) * PST + quad * 8];
      short8 kf1 = *(const short8*)&sK[(n * 16 + l16) * PST + 32 + quad * 8];
      f32x4 s = (f32x4){0.f, 0.f, 0.f, 0.f};
      s = __builtin_amdgcn_mfma_f32_16x16x32_bf16(kf0, qf0, s, 0, 0, 0);
      s = __builtin_amdgcn_mfma_f32_16x16x32_bf16(kf1, qf1, s, 0, 0, 0);
      float e0, e1, e2, e3;
      if (full) {
        e0 = exp2f(s[0]); e1 = exp2f(s[1]);
        e2 = exp2f(s[2]); e3 = exp2f(s[3]);
      } else {
        int kb = kt * 64 + n * 16 + quad * 4;
        e0 = (kb + 0 < len) ? exp2f(s[0]) : 0.f;
        e1 = (kb + 1 < len) ? exp2f(s[1]) : 0.f;
        e2 = (kb + 2 < len) ? exp2f(s[2]) : 0.f;
        e3 = (kb + 3 < len) ? exp2f(s[3]) : 0.f;
      }
      den += (e0 + e1) + (e2 + e3);
      u32x2 pk;
      pk[0] = __builtin_amdgcn_perm(fbits(e1), fbits(e0), 0x07060302);
      pk[1] = __builtin_amdgcn_perm(fbits(e3), fbits(e2), 0x07060302);
      *(u32x2*)&sP[(w * 16 + l16) * PST + n * 16 + quad * 4] = pk;
    }
    // sP rows are per-wave -> no barrier before PV

    // ctx^T += V^T . P^T : D[d=quad*4+j][q=l16]
    short8 pf0 = *(const short8*)&sP[(w * 16 + l16) * PST + quad * 8];
    short8 pf1 = *(const short8*)&sP[(w * 16 + l16) * PST + 32 + quad * 8];
    for (int n2 = 0; n2 < 4; ++n2) {
      short8 vf0 = *(const short8*)&sVT[(n2 * 16 + l16) * PST + quad * 8];
      short8 vf1 = *(const short8*)&sVT[(n2 * 16 + l16) * PST + 32 + quad * 8];
      accpv[n2] = __builtin_amdgcn_mfma_f32_16x16x32_bf16(vf0, pf0, accpv[n2], 0, 0, 0);
      accpv[n2] = __builtin_amdgcn_mfma_f32_16x16x32_bf16(vf1, pf1, accpv[n2], 0, 0, 0);
    }
  }

  den += __shfl_xor(den, 16, 64);
  den += __shfl_xor(den, 32, 64);
  float inv = 1.f / (den + 1e-8f);

  {
    int q = qt * 64 + w * 16 + l16;
    float* dst = ctx + (size_t)(b * SEQ + q) * D_MODEL + h * D_KH;
    for (int n2 = 0; n2 < 4; ++n2) {
      f32x4 o = accpv[n2];
      float4 v = make_float4(o[0] * inv, o[1] * inv, o[2] * inv, o[3] * inv);
      *(float4*)(dst + n2 * 16 + quad * 4) = v;
    }
  }
}

// ---------------------------------------------------------------- launch
extern "C" void kernel_launch(void* const* d_in, const int* in_sizes, int n_in,
                              void* d_out, int out_size, void* d_ws, size_t ws_size,
                              hipStream_t stream) {
  const float* Q      = (const float*)d_in[0];
  const int*   length = (const int*)d_in[1];
  const float* Wq     = (const float*)d_in[2];
  const float* bq     = (const float*)d_in[3];
  const float* Wk     = (const float*)d_in[4];
  const float* bk     = (const float*)d_in[5];
  const float* Wv     = (const float*)d_in[6];
  const float* bv     = (const float*)d_in[7];

  float* out_ctx = (float*)d_out;                         // [8192,1024]
  float* out_qa  = out_ctx + (size_t)M_TOTAL * D_MODEL;   // [8192,1024]

  char* ws = (char*)d_ws;
  unsigned short* Qbf = (unsigned short*)ws;                              // 16 MB
  unsigned short* WT  = (unsigned short*)(ws + (size_t)16 * 1024 * 1024); //  6 MB
  unsigned short* Kbf = (unsigned short*)(ws + (size_t)22 * 1024 * 1024); // 16 MB
  unsigned short* Vt  = (unsigned short*)(ws + (size_t)38 * 1024 * 1024); // 16 MB

  hipLaunchKernelGGL(cvt_q, dim3((M_TOTAL * D_MODEL) / (256 * 4)), dim3(256), 0, stream,
                     Q, Qbf);
  hipLaunchKernelGGL(cvt_wt, dim3(32, 32, 3), dim3(256), 0, stream, Wq, Wk, Wv, WT);
  hipLaunchKernelGGL(gemm_qkv, dim3(D_MODEL / BN, M_TOTAL / BM, 3), dim3(256), 0, stream,
                     Qbf, WT, bq, bk, bv, out_qa, Kbf, Vt);
  hipLaunchKernelGGL(attn, dim3(SEQ / 64, BATCH * N_HEADS), dim3(256), 0, stream,
                     out_qa, Kbf, Vt, length, out_ctx);
}